// Round 1
// baseline (599.456 us; speedup 1.0000x reference)
//
#include <hip/hip_runtime.h>
#include <math.h>

typedef unsigned short u16;
typedef unsigned int   u32;

#define S2 0.70710678118654752440f

__device__ __forceinline__ float bf2f(u16 u){
  union { u32 i; float f; } v; v.i = ((u32)u) << 16; return v.f;
}
__device__ __forceinline__ u16 f2bf(float f){
  union { float f; u32 i; } v; v.f = f;
  u32 r = v.i + 0x7FFFu + ((v.i >> 16) & 1u);
  return (u16)(r >> 16);
}

struct C2 { float r, i; };

// forward 8-pt complex FFT (twiddle e^{-2pi i k/8}), in place
__device__ __forceinline__ void fft8_fwd(C2* y){
  C2 a0 = {y[0].r+y[4].r, y[0].i+y[4].i};
  C2 a1 = {y[0].r-y[4].r, y[0].i-y[4].i};
  C2 a2 = {y[2].r+y[6].r, y[2].i+y[6].i};
  C2 a3 = {y[2].r-y[6].r, y[2].i-y[6].i};
  C2 b0 = {y[1].r+y[5].r, y[1].i+y[5].i};
  C2 b1 = {y[1].r-y[5].r, y[1].i-y[5].i};
  C2 b2 = {y[3].r+y[7].r, y[3].i+y[7].i};
  C2 b3 = {y[3].r-y[7].r, y[3].i-y[7].i};
  C2 E0 = {a0.r+a2.r, a0.i+a2.i};
  C2 E2 = {a0.r-a2.r, a0.i-a2.i};
  C2 E1 = {a1.r+a3.i, a1.i-a3.r};   // a1 - i*a3
  C2 E3 = {a1.r-a3.i, a1.i+a3.r};   // a1 + i*a3
  C2 O0 = {b0.r+b2.r, b0.i+b2.i};
  C2 O2 = {b0.r-b2.r, b0.i-b2.i};
  C2 O1 = {b1.r+b3.i, b1.i-b3.r};
  C2 O3 = {b1.r-b3.i, b1.i+b3.r};
  C2 t1 = {S2*(O1.r+O1.i), S2*(O1.i-O1.r)};   // w1*O1, w1=(s,-s)
  C2 t2 = {O2.i, -O2.r};                      // -i*O2
  C2 t3 = {S2*(O3.i-O3.r), -S2*(O3.r+O3.i)};  // w3*O3, w3=(-s,-s)
  y[0].r=E0.r+O0.r; y[0].i=E0.i+O0.i;
  y[4].r=E0.r-O0.r; y[4].i=E0.i-O0.i;
  y[1].r=E1.r+t1.r; y[1].i=E1.i+t1.i;
  y[5].r=E1.r-t1.r; y[5].i=E1.i-t1.i;
  y[2].r=E2.r+t2.r; y[2].i=E2.i+t2.i;
  y[6].r=E2.r-t2.r; y[6].i=E2.i-t2.i;
  y[3].r=E3.r+t3.r; y[3].i=E3.i+t3.i;
  y[7].r=E3.r-t3.r; y[7].i=E3.i-t3.i;
}

// inverse 8-pt complex FFT (twiddle e^{+2pi i nk/8}), NO 1/8 scaling, in place
__device__ __forceinline__ void fft8_inv(C2* z){
  C2 A0 = {z[0].r+z[4].r, z[0].i+z[4].i};
  C2 A1 = {z[1].r+z[5].r, z[1].i+z[5].i};
  C2 A2 = {z[2].r+z[6].r, z[2].i+z[6].i};
  C2 A3 = {z[3].r+z[7].r, z[3].i+z[7].i};
  C2 D0 = {z[0].r-z[4].r, z[0].i-z[4].i};
  C2 D1 = {z[1].r-z[5].r, z[1].i-z[5].i};
  C2 D2 = {z[2].r-z[6].r, z[2].i-z[6].i};
  C2 D3 = {z[3].r-z[7].r, z[3].i-z[7].i};
  C2 B0 = D0;
  C2 B1 = {S2*(D1.r-D1.i), S2*(D1.i+D1.r)};   // u1*D1, u1=(s,s)
  C2 B2 = {-D2.i, D2.r};                      // i*D2
  C2 B3 = {-S2*(D3.r+D3.i), S2*(D3.r-D3.i)};  // u3*D3, u3=(-s,s)
  z[0].r = A0.r+A1.r+A2.r+A3.r;           z[0].i = A0.i+A1.i+A2.i+A3.i;
  z[2].r = A0.r-A2.r-(A1.i-A3.i);         z[2].i = A0.i-A2.i+(A1.r-A3.r);
  z[4].r = A0.r-A1.r+A2.r-A3.r;           z[4].i = A0.i-A1.i+A2.i-A3.i;
  z[6].r = A0.r-A2.r+(A1.i-A3.i);         z[6].i = A0.i-A2.i-(A1.r-A3.r);
  z[1].r = B0.r+B1.r+B2.r+B3.r;           z[1].i = B0.i+B1.i+B2.i+B3.i;
  z[3].r = B0.r-B2.r-(B1.i-B3.i);         z[3].i = B0.i-B2.i+(B1.r-B3.r);
  z[5].r = B0.r-B1.r+B2.r-B3.r;           z[5].i = B0.i-B1.i+B2.i-B3.i;
  z[7].r = B0.r-B2.r+(B1.i-B3.i);         z[7].i = B0.i-B2.i-(B1.r-B3.r);
}

// real 8-pt rfft in place; out packed {X0, X4, re1, im1, re2, im2, re3, im3}
__device__ __forceinline__ void rfft8_row(float* x){
  float et0=x[0]+x[4], et1=x[0]-x[4], et2=x[2]+x[6], et3=x[2]-x[6];
  float ot0=x[1]+x[5], ot1=x[1]-x[5], ot2=x[3]+x[7], ot3=x[3]-x[7];
  float E0=et0+et2, E2=et0-et2;
  float O0=ot0+ot2, O2=ot0-ot2;
  float om=S2*(ot1-ot3), op=S2*(ot1+ot3);
  x[0]=E0+O0;  x[1]=E0-O0;      // X0 , X4
  x[2]=et1+om; x[3]=-et3-op;    // X1
  x[4]=E2;     x[5]=-O2;        // X2
  x[6]=et1-om; x[7]=et3-op;     // X3
}

// irfft of 5 bins -> 8 reals, uses Re only of bins 0/4 (numpy semantics), /64 folded in
__device__ __forceinline__ void irfft8_row(float f0, C2 R1, C2 R2, C2 R3, float f4, float* x){
  float A0  = f0+f4, B0v = f0-f4;
  float A1r = R1.r+R3.r, A1i = R1.i-R3.i;
  float A2  = 2.f*R2.r;
  float D1r = R1.r-R3.r, D1i = R1.i+R3.i;
  float B1r = S2*(D1r-D1i), B1i = S2*(D1i+D1r);
  float B2  = -2.f*R2.i;
  const float k = 1.f/64.f;
  x[0]=k*(A0 +A2+2.f*A1r); x[2]=k*(A0 -A2-2.f*A1i);
  x[4]=k*(A0 +A2-2.f*A1r); x[6]=k*(A0 -A2+2.f*A1i);
  x[1]=k*(B0v+B2+2.f*B1r); x[3]=k*(B0v-B2-2.f*B1i);
  x[5]=k*(B0v+B2-2.f*B1r); x[7]=k*(B0v-B2+2.f*B1i);
}

// ---------------- K_prep: transpose w_out (64x64) ----------------
__global__ void k_prep(const float* __restrict__ w_out, float* __restrict__ wT){
  int i = blockIdx.x*256 + threadIdx.x;   // 4096
  int o = i >> 6, c = i & 63;
  wT[c*64 + o] = w_out[o*64 + c];
}

// ---------------- K_front: 1x1 convs + patch FFT section ----------------
// block = 2 horizontally adjacent 8x8 patches, 256 threads.
// y layout (bf16): [b][ph(32)][pw(32)][k=r*8+col (64)][c (128)]
__global__ __launch_bounds__(256, 2)
void k_front(const float* __restrict__ img, const float* __restrict__ evt,
             const float* __restrict__ w_img, const float* __restrict__ w_evt,
             const float* __restrict__ filt, u16* __restrict__ yout){
  __shared__ __align__(16) u16 smem[32768];   // 64 KB total
  u16* s_in  = smem;            // [T(2)][ci(64)][pp(128)] bf16 inputs
  u16* s_out = smem + 16384;    // swizzled spectrum buffer [pc(2)][c(128)][64], also reused as stage

  const int t   = threadIdx.x;
  const int bid = blockIdx.x;          // 2048 = b(4) * ph(32) * bx(16)
  const int b   = bid >> 9;
  const int ph  = (bid >> 4) & 31;
  const int bx  = bid & 15;

  // ---- load inputs fp32 -> bf16 LDS ----
  #pragma unroll
  for (int i=0;i<16;i++){
    int idx = t + 256*i;
    const int T = i >> 3;             // 0: img, 1: evt
    int r2 = idx & 2047;
    int ci = r2 >> 5;
    int q  = r2 & 31;
    int row = q >> 2, j = q & 3;
    const float* sp = (T==0 ? img : evt)
        + (((size_t)(b*64 + ci)*256 + ph*8 + row)*256 + bx*16 + j*4);
    float4 v = *(const float4*)sp;
    u32 lo = ((u32)f2bf(v.y)<<16) | (u32)f2bf(v.x);
    u32 hi = ((u32)f2bf(v.w)<<16) | (u32)f2bf(v.z);
    int u = (T*64+ci)*128 + (j>>1)*64 + row*8 + (j&1)*4;
    ((u32*)&s_in[u])[0] = lo;
    ((u32*)&s_in[u])[1] = hi;
  }
  __syncthreads();

  const int wv   = __builtin_amdgcn_readfirstlane(t >> 6);
  const int lane = t & 63;
  const int gP   = wv >> 1;           // gemm patch (0/1)
  const int gC   = (wv & 1) * 64;     // gemm channel half
  const int pc   = t >> 7;            // fft patch (0/1)
  const int c    = t & 127;           // fft channel

  // ---- GEMM event: evt_ = W_evt @ evt ----
  {
    #pragma unroll
    for (int ps=0; ps<8; ps++){
      int c0 = gC + ps*8;
      float acc[8] = {0.f,0.f,0.f,0.f,0.f,0.f,0.f,0.f};
      #pragma unroll 8
      for (int ci=0; ci<64; ci++){
        float v = bf2f(s_in[(64+ci)*128 + gP*64 + lane]);
        #pragma unroll
        for (int jj=0;jj<8;jj++)
          acc[jj] = fmaf(w_evt[(c0+jj)*64+ci], v, acc[jj]);
      }
      #pragma unroll
      for (int jj=0;jj<8;jj++){
        int cch = c0+jj;
        int d = cch*32 + (((lane>>1) + cch) & 31);    // rotation swizzle
        s_out[gP*8192 + d*2 + (lane&1)] = f2bf(acc[jj]);
      }
    }
  }
  __syncthreads();

  // ---- FFT phase 1: Fe = rfft2(evt_), fef = Fe * filter ----
  C2 fef[8][5];
  {
    float p[64];
    const u32* sod = (const u32*)s_out + pc*4096 + c*32;
    #pragma unroll
    for (int d=0; d<32; d++){
      u32 v = sod[(d + c) & 31];
      p[2*d]   = bf2f((u16)(v & 0xFFFFu));
      p[2*d+1] = bf2f((u16)(v >> 16));
    }
    #pragma unroll
    for (int r=0;r<8;r++) rfft8_row(&p[r*8]);
    const float* fl = filt + c*40;
    #pragma unroll
    for (int j=0;j<5;j++){
      C2 y[8];
      #pragma unroll
      for (int r=0;r<8;r++){
        float re = (j==0) ? p[r*8] : (j==4) ? p[r*8+1] : p[r*8+2*j];
        float im = (j==0 || j==4) ? 0.f : p[r*8+2*j+1];
        y[r].r = re; y[r].i = im;
      }
      fft8_fwd(y);
      #pragma unroll
      for (int ky=0;ky<8;ky++){
        float f = fl[ky*5+j];
        fef[ky][j].r = y[ky].r * f;
        fef[ky][j].i = y[ky].i * f;
      }
    }
  }
  __syncthreads();

  // ---- GEMM img: img_ = W_img @ img ----
  {
    #pragma unroll
    for (int ps=0; ps<8; ps++){
      int c0 = gC + ps*8;
      float acc[8] = {0.f,0.f,0.f,0.f,0.f,0.f,0.f,0.f};
      #pragma unroll 8
      for (int ci=0; ci<64; ci++){
        float v = bf2f(s_in[ci*128 + gP*64 + lane]);
        #pragma unroll
        for (int jj=0;jj<8;jj++)
          acc[jj] = fmaf(w_img[(c0+jj)*64+ci], v, acc[jj]);
      }
      #pragma unroll
      for (int jj=0;jj<8;jj++){
        int cch = c0+jj;
        int d = cch*32 + (((lane>>1) + cch) & 31);
        s_out[gP*8192 + d*2 + (lane&1)] = f2bf(acc[jj]);
      }
    }
  }
  __syncthreads();

  // ---- FFT phase 2: X = (Fi+1)*fef ; x = irfft2(X) ----
  {
    float p[64];
    const u32* sod = (const u32*)s_out + pc*4096 + c*32;
    #pragma unroll
    for (int d=0; d<32; d++){
      u32 v = sod[(d + c) & 31];
      p[2*d]   = bf2f((u16)(v & 0xFFFFu));
      p[2*d+1] = bf2f((u16)(v >> 16));
    }
    #pragma unroll
    for (int r=0;r<8;r++) rfft8_row(&p[r*8]);
    #pragma unroll
    for (int j=0;j<5;j++){
      C2 y[8];
      #pragma unroll
      for (int r=0;r<8;r++){
        float re = (j==0) ? p[r*8] : (j==4) ? p[r*8+1] : p[r*8+2*j];
        float im = (j==0 || j==4) ? 0.f : p[r*8+2*j+1];
        y[r].r = re; y[r].i = im;
      }
      fft8_fwd(y);
      #pragma unroll
      for (int ky=0;ky<8;ky++){
        C2 e = fef[ky][j];
        C2 a = y[ky];
        fef[ky][j].r = a.r*e.r - a.i*e.i + e.r;
        fef[ky][j].i = a.r*e.i + a.i*e.r + e.i;
      }
    }
    // inverse column FFTs
    #pragma unroll
    for (int j=0;j<5;j++){
      C2 z[8];
      #pragma unroll
      for (int ky=0;ky<8;ky++) z[ky] = fef[ky][j];
      fft8_inv(z);
      #pragma unroll
      for (int ky=0;ky<8;ky++) fef[ky][j] = z[ky];
    }
    // inverse row rffts -> spatial (scaled 1/64)
    #pragma unroll
    for (int r=0;r<8;r++)
      irfft8_row(fef[r][0].r, fef[r][1], fef[r][2], fef[r][3], fef[r][4].r, &p[r*8]);

    __syncthreads();   // all reads of s_out done; safe to overwrite as stage
    // stage: [pc][k][c] bf16 (== global y order for this block)
    #pragma unroll
    for (int k=0;k<64;k++)
      s_out[(pc*64 + k)*128 + c] = f2bf(p[k]);
  }
  __syncthreads();

  // ---- coalesced store of the 2-patch stage (32 KB) ----
  {
    const uint4* sg = (const uint4*)s_out;
    uint4* dst = (uint4*)(yout + (size_t)(b*1024 + ph*32 + bx*2)*8192);
    #pragma unroll
    for (int i=0;i<8;i++){
      int q2 = t + 256*i;
      dst[q2] = sg[q2];
    }
  }
}

// ---------------- K_back: dw3x3 + gelu-gate + 1x1 out ----------------
// block = 16x16 pixel tile (2x2 patches), 256 threads
__global__ __launch_bounds__(256, 3)
void k_back(const u16* __restrict__ y, const float* __restrict__ wdw,
            const float* __restrict__ wT, float* __restrict__ out){
  __shared__ u16 L[64*18*20];     // 45 KB: [row(64)][yy(18)][xx(20)]
  const int t   = threadIdx.x;
  const int bid = blockIdx.x;     // 1024 = b(4) * ty(16) * tx(16)
  const int b   = bid >> 8;
  const int ty  = (bid >> 4) & 15;
  const int tx  = bid & 15;
  const int ph0 = ty*2, pw0 = tx*2;
  const int y_  = t >> 4, x_ = t & 15;

  float acc[64];
  #pragma unroll
  for (int i=0;i<64;i++) acc[i] = 0.f;

  // zero LDS once (out-of-image halo cells stay 0 for both chunks)
  {
    u32* L4 = (u32*)L;
    for (int i=t; i<11520; i+=256) L4[i] = 0u;
  }
  __syncthreads();

  for (int chunk=0; chunk<2; chunk++){
    // ---- interior load: 2 grp * 4 patches * 64 k * 4 lane4 = 2048 tasks ----
    #pragma unroll
    for (int i=0;i<8;i++){
      int task = t + 256*i;
      int grp = task >> 10;
      int r1  = task & 1023;
      int seg = r1 >> 2, l4 = r1 & 3;
      int pp  = seg >> 6, k = seg & 63;
      int pr  = pp >> 1, pcc = pp & 1;
      int cbase = chunk*32 + grp*64 + l4*8;
      const uint4* src = (const uint4*)(y +
          ((((size_t)b*1024 + (size_t)(ph0+pr)*32 + (pw0+pcc))*64 + k)*128 + cbase));
      uint4 v = *src;
      int row0 = grp*32 + l4*8;
      int yy = 1 + pr*8 + (k>>3);
      int xx = 2 + pcc*8 + (k&7);
      u32 w0=v.x, w1=v.y, w2=v.z, w3=v.w;
      L[(row0+0)*360 + yy*20 + xx] = (u16)(w0 & 0xFFFFu);
      L[(row0+1)*360 + yy*20 + xx] = (u16)(w0 >> 16);
      L[(row0+2)*360 + yy*20 + xx] = (u16)(w1 & 0xFFFFu);
      L[(row0+3)*360 + yy*20 + xx] = (u16)(w1 >> 16);
      L[(row0+4)*360 + yy*20 + xx] = (u16)(w2 & 0xFFFFu);
      L[(row0+5)*360 + yy*20 + xx] = (u16)(w2 >> 16);
      L[(row0+6)*360 + yy*20 + xx] = (u16)(w3 & 0xFFFFu);
      L[(row0+7)*360 + yy*20 + xx] = (u16)(w3 >> 16);
    }
    // ---- halo load: 2 grp * 68 segs * 4 lane4 = 544 tasks ----
    for (int i=0;i<3;i++){
      int task = t + 256*i;
      if (task < 544){
        int grp = (task >= 272) ? 1 : 0;
        int u2  = task - grp*272;
        int seg = u2 >> 2, l4 = u2 & 3;
        int sph, spw, k, yy, xx;
        if (seg < 16){ int pcx=seg>>3, col=seg&7; sph=ph0-1; spw=pw0+pcx; k=56+col; yy=0;  xx=2+pcx*8+col; }
        else if (seg < 32){ int s2=seg-16; int pcx=s2>>3, col=s2&7; sph=ph0+2; spw=pw0+pcx; k=col; yy=17; xx=2+pcx*8+col; }
        else if (seg < 48){ int s2=seg-32; int pr=s2>>3, r=s2&7; sph=ph0+pr; spw=pw0-1; k=r*8+7; yy=1+pr*8+r; xx=1; }
        else if (seg < 64){ int s2=seg-48; int pr=s2>>3, r=s2&7; sph=ph0+pr; spw=pw0+2; k=r*8;   yy=1+pr*8+r; xx=18; }
        else { int cid=seg-64;
               sph = (cid<2) ? ph0-1 : ph0+2;
               spw = (cid&1) ? pw0+2 : pw0-1;
               k   = (cid==0)?63:(cid==1)?56:(cid==2)?7:0;
               yy  = (cid<2)?0:17;
               xx  = (cid&1)?18:1; }
        if (sph>=0 && sph<=31 && spw>=0 && spw<=31){
          int cbase = chunk*32 + grp*64 + l4*8;
          const uint4* src = (const uint4*)(y +
              ((((size_t)b*1024 + (size_t)sph*32 + spw)*64 + k)*128 + cbase));
          uint4 v = *src;
          int row0 = grp*32 + l4*8;
          u32 w0=v.x, w1=v.y, w2=v.z, w3=v.w;
          L[(row0+0)*360 + yy*20 + xx] = (u16)(w0 & 0xFFFFu);
          L[(row0+1)*360 + yy*20 + xx] = (u16)(w0 >> 16);
          L[(row0+2)*360 + yy*20 + xx] = (u16)(w1 & 0xFFFFu);
          L[(row0+3)*360 + yy*20 + xx] = (u16)(w1 >> 16);
          L[(row0+4)*360 + yy*20 + xx] = (u16)(w2 & 0xFFFFu);
          L[(row0+5)*360 + yy*20 + xx] = (u16)(w2 >> 16);
          L[(row0+6)*360 + yy*20 + xx] = (u16)(w3 & 0xFFFFu);
          L[(row0+7)*360 + yy*20 + xx] = (u16)(w3 >> 16);
        }
      }
    }
    __syncthreads();

    // ---- compute: dw3x3 (pair), gelu-gate, accumulate 1x1 out ----
    for (int cc=0; cc<32; cc++){
      int clo = chunk*32 + cc;
      const float* w1p = wdw + clo*9;
      const float* w2p = wdw + (clo+64)*9;
      float d1 = 0.f, d2 = 0.f;
      #pragma unroll
      for (int dy=0; dy<3; dy++){
        #pragma unroll
        for (int dx=0; dx<3; dx++){
          d1 = fmaf(w1p[dy*3+dx], bf2f(L[cc*360      + (y_+dy)*20 + (x_+1+dx)]), d1);
          d2 = fmaf(w2p[dy*3+dx], bf2f(L[(32+cc)*360 + (y_+dy)*20 + (x_+1+dx)]), d2);
        }
      }
      float g = 0.5f * d1 * (1.f + erff(d1 * 0.70710678118654752f));
      float a = g * d2;
      const float* wr = wT + clo*64;
      #pragma unroll
      for (int co=0; co<64; co++)
        acc[co] = fmaf(wr[co], a, acc[co]);
    }
    __syncthreads();
  }

  // ---- store ----
  const int gy = ty*16 + y_;
  const int gx = tx*16 + x_;
  float* op = out + (size_t)b*64*65536 + (size_t)gy*256 + gx;
  #pragma unroll
  for (int co=0; co<64; co++)
    op[(size_t)co*65536] = acc[co];
}

extern "C" void kernel_launch(void* const* d_in, const int* in_sizes, int n_in,
                              void* d_out, int out_size, void* d_ws, size_t ws_size,
                              hipStream_t stream){
  const float* img   = (const float*)d_in[0];
  const float* evt   = (const float*)d_in[1];
  const float* w_img = (const float*)d_in[2];
  const float* w_evt = (const float*)d_in[3];
  const float* w_dw  = (const float*)d_in[4];
  const float* filt  = (const float*)d_in[5];
  const float* w_out = (const float*)d_in[6];
  float* out = (float*)d_out;

  float* wT = (float*)d_ws;                       // 16 KB
  u16*   y  = (u16*)((char*)d_ws + 16384);        // 67.1 MB bf16 intermediate

  k_prep<<<16, 256, 0, stream>>>(w_out, wT);
  k_front<<<2048, 256, 0, stream>>>(img, evt, w_img, w_evt, filt, y);
  k_back<<<1024, 256, 0, stream>>>(y, w_dw, wT, out);
}

// Round 2
// 489.532 us; speedup vs baseline: 1.2246x; 1.2246x over previous
//
#include <hip/hip_runtime.h>
#include <math.h>

typedef unsigned short u16;
typedef unsigned int   u32;

#define S2 0.70710678118654752440f

typedef float f32x4 __attribute__((ext_vector_type(4)));
typedef short bf16x8 __attribute__((ext_vector_type(8)));
#define MFMA(a,b,c) __builtin_amdgcn_mfma_f32_16x16x32_bf16(a,b,c,0,0,0)

__device__ __forceinline__ float bf2f(u16 u){
  union { u32 i; float f; } v; v.i = ((u32)u) << 16; return v.f;
}
__device__ __forceinline__ u16 f2bf(float f){
  union { float f; u32 i; } v; v.f = f;
  u32 r = v.i + 0x7FFFu + ((v.i >> 16) & 1u);
  return (u16)(r >> 16);
}

struct C2 { float r, i; };

__device__ __forceinline__ void fft8_fwd(C2* y){
  C2 a0 = {y[0].r+y[4].r, y[0].i+y[4].i};
  C2 a1 = {y[0].r-y[4].r, y[0].i-y[4].i};
  C2 a2 = {y[2].r+y[6].r, y[2].i+y[6].i};
  C2 a3 = {y[2].r-y[6].r, y[2].i-y[6].i};
  C2 b0 = {y[1].r+y[5].r, y[1].i+y[5].i};
  C2 b1 = {y[1].r-y[5].r, y[1].i-y[5].i};
  C2 b2 = {y[3].r+y[7].r, y[3].i+y[7].i};
  C2 b3 = {y[3].r-y[7].r, y[3].i-y[7].i};
  C2 E0 = {a0.r+a2.r, a0.i+a2.i};
  C2 E2 = {a0.r-a2.r, a0.i-a2.i};
  C2 E1 = {a1.r+a3.i, a1.i-a3.r};
  C2 E3 = {a1.r-a3.i, a1.i+a3.r};
  C2 O0 = {b0.r+b2.r, b0.i+b2.i};
  C2 O2 = {b0.r-b2.r, b0.i-b2.i};
  C2 O1 = {b1.r+b3.i, b1.i-b3.r};
  C2 O3 = {b1.r-b3.i, b1.i+b3.r};
  C2 t1 = {S2*(O1.r+O1.i), S2*(O1.i-O1.r)};
  C2 t2 = {O2.i, -O2.r};
  C2 t3 = {S2*(O3.i-O3.r), -S2*(O3.r+O3.i)};
  y[0].r=E0.r+O0.r; y[0].i=E0.i+O0.i;
  y[4].r=E0.r-O0.r; y[4].i=E0.i-O0.i;
  y[1].r=E1.r+t1.r; y[1].i=E1.i+t1.i;
  y[5].r=E1.r-t1.r; y[5].i=E1.i-t1.i;
  y[2].r=E2.r+t2.r; y[2].i=E2.i+t2.i;
  y[6].r=E2.r-t2.r; y[6].i=E2.i-t2.i;
  y[3].r=E3.r+t3.r; y[3].i=E3.i+t3.i;
  y[7].r=E3.r-t3.r; y[7].i=E3.i-t3.i;
}

__device__ __forceinline__ void fft8_inv(C2* z){
  C2 A0 = {z[0].r+z[4].r, z[0].i+z[4].i};
  C2 A1 = {z[1].r+z[5].r, z[1].i+z[5].i};
  C2 A2 = {z[2].r+z[6].r, z[2].i+z[6].i};
  C2 A3 = {z[3].r+z[7].r, z[3].i+z[7].i};
  C2 D0 = {z[0].r-z[4].r, z[0].i-z[4].i};
  C2 D1 = {z[1].r-z[5].r, z[1].i-z[5].i};
  C2 D2 = {z[2].r-z[6].r, z[2].i-z[6].i};
  C2 D3 = {z[3].r-z[7].r, z[3].i-z[7].i};
  C2 B0 = D0;
  C2 B1 = {S2*(D1.r-D1.i), S2*(D1.i+D1.r)};
  C2 B2 = {-D2.i, D2.r};
  C2 B3 = {-S2*(D3.r+D3.i), S2*(D3.r-D3.i)};
  z[0].r = A0.r+A1.r+A2.r+A3.r;           z[0].i = A0.i+A1.i+A2.i+A3.i;
  z[2].r = A0.r-A2.r-(A1.i-A3.i);         z[2].i = A0.i-A2.i+(A1.r-A3.r);
  z[4].r = A0.r-A1.r+A2.r-A3.r;           z[4].i = A0.i-A1.i+A2.i-A3.i;
  z[6].r = A0.r-A2.r+(A1.i-A3.i);         z[6].i = A0.i-A2.i-(A1.r-A3.r);
  z[1].r = B0.r+B1.r+B2.r+B3.r;           z[1].i = B0.i+B1.i+B2.i+B3.i;
  z[3].r = B0.r-B2.r-(B1.i-B3.i);         z[3].i = B0.i-B2.i+(B1.r-B3.r);
  z[5].r = B0.r-B1.r+B2.r-B3.r;           z[5].i = B0.i-B1.i+B2.i-B3.i;
  z[7].r = B0.r-B2.r+(B1.i-B3.i);         z[7].i = B0.i-B2.i-(B1.r-B3.r);
}

__device__ __forceinline__ void rfft8_row(float* x){
  float et0=x[0]+x[4], et1=x[0]-x[4], et2=x[2]+x[6], et3=x[2]-x[6];
  float ot0=x[1]+x[5], ot1=x[1]-x[5], ot2=x[3]+x[7], ot3=x[3]-x[7];
  float E0=et0+et2, E2=et0-et2;
  float O0=ot0+ot2, O2=ot0-ot2;
  float om=S2*(ot1-ot3), op=S2*(ot1+ot3);
  x[0]=E0+O0;  x[1]=E0-O0;
  x[2]=et1+om; x[3]=-et3-op;
  x[4]=E2;     x[5]=-O2;
  x[6]=et1-om; x[7]=et3-op;
}

__device__ __forceinline__ void irfft8_row(float f0, C2 R1, C2 R2, C2 R3, float f4, float* x){
  float A0  = f0+f4, B0v = f0-f4;
  float A1r = R1.r+R3.r, A1i = R1.i-R3.i;
  float A2  = 2.f*R2.r;
  float D1r = R1.r-R3.r, D1i = R1.i+R3.i;
  float B1r = S2*(D1r-D1i), B1i = S2*(D1i+D1r);
  float B2  = -2.f*R2.i;
  const float k = 1.f/64.f;
  x[0]=k*(A0 +A2+2.f*A1r); x[2]=k*(A0 -A2-2.f*A1i);
  x[4]=k*(A0 +A2-2.f*A1r); x[6]=k*(A0 -A2+2.f*A1i);
  x[1]=k*(B0v+B2+2.f*B1r); x[3]=k*(B0v-B2-2.f*B1i);
  x[5]=k*(B0v+B2-2.f*B1r); x[7]=k*(B0v-B2+2.f*B1i);
}

// ---------------- K_prep: fp32 weights -> bf16 ----------------
__global__ void k_prep(const float* __restrict__ wi, const float* __restrict__ we,
                       const float* __restrict__ wo,
                       u16* __restrict__ wbi, u16* __restrict__ wbe, u16* __restrict__ wbo){
  int i = blockIdx.x*256 + threadIdx.x;   // 20480
  if (i < 8192)        wbi[i]        = f2bf(wi[i]);
  else if (i < 16384)  wbe[i-8192]   = f2bf(we[i-8192]);
  else if (i < 20480)  wbo[i-16384]  = f2bf(wo[i-16384]);
}

// ---------------- K_front: 1x1 convs (MFMA) + patch FFT ----------------
// block = 2 horizontal patches (128 pixels), 256 threads
// y layout (bf16): [b][ph(32)][pw(32)][k=r*8+col (64)][c (128)]
__global__ __launch_bounds__(256, 3)
void k_front(const float* __restrict__ img, const float* __restrict__ evt,
             const u16* __restrict__ wbi, const u16* __restrict__ wbe,
             const float* __restrict__ filt, u16* __restrict__ yout){
  __shared__ __align__(16) u16 s_a[8192];      // 16 KB  [pix(128)][c(64)] xor-swizzled
  __shared__ __align__(16) u16 s_spec[16384];  // 32 KB  [och(128)][pix(128)] xor-swizzled / stage

  const int t   = threadIdx.x;
  const int bid = blockIdx.x;          // 2048 = b(4) * ph(32) * bx(16)
  const int b   = bid >> 9;
  const int ph  = (bid >> 4) & 31;
  const int bx  = bid & 15;
  const int wv   = t >> 6;
  const int quad = (t >> 4) & 3;
  const int ln15 = t & 15;
  const int pc   = t >> 7;             // fft patch (0/1)
  const int c    = t & 127;            // fft channel

  // stage fp32 global -> bf16 pixel-major LDS (K-contiguous for MFMA A)
  auto do_stage = [&](const float* src){
    #pragma unroll
    for (int i=0;i<8;i++){
      int task = t + 256*i;
      int ci = task>>5, q = task&31;
      int r = q>>2, j = q&3;
      const float4 v = *(const float4*)(src +
          (((size_t)(b*64+ci)*256 + ph*8 + r)*256 + bx*16 + j*4));
      int p0 = (j>>1)*64 + r*8 + (j&1)*4;
      int gbase = ci>>3, cl = ci&7;
      float vv[4] = {v.x, v.y, v.z, v.w};
      #pragma unroll
      for (int w=0;w<4;w++){
        int p = p0+w;
        int g = gbase ^ (p&7) ^ r;          // r == (p>>3)&7
        s_a[p*64 + g*8 + cl] = f2bf(vv[w]);
      }
    }
  };

  // MFMA GEMM: C[pix 128][och 128] = s_a[pix][c] * W[och][c], write bf16 -> s_spec
  auto do_gemm = [&](const u16* __restrict__ wb){
    f32x4 acc[2][8];
    #pragma unroll
    for (int nt=0;nt<2;nt++)
      #pragma unroll
      for (int mt=0;mt<8;mt++)
        acc[nt][mt] = (f32x4){0.f,0.f,0.f,0.f};
    const int nb = wv*32;
    #pragma unroll
    for (int kk=0;kk<2;kk++){
      bf16x8 bf0 = *(const bf16x8*)&wb[(nb      + ln15)*64 + kk*32 + quad*8];
      bf16x8 bf1 = *(const bf16x8*)&wb[(nb + 16 + ln15)*64 + kk*32 + quad*8];
      #pragma unroll
      for (int mt=0;mt<8;mt++){
        int pix = mt*16 + ln15;
        int g = (kk*4+quad) ^ (pix&7) ^ ((pix>>3)&7);
        bf16x8 af = *(const bf16x8*)&s_a[pix*64 + g*8];
        acc[0][mt] = MFMA(af, bf0, acc[0][mt]);
        acc[1][mt] = MFMA(af, bf1, acc[1][mt]);
      }
    }
    #pragma unroll
    for (int nt=0;nt<2;nt++){
      int och = nb + nt*16 + ln15;
      #pragma unroll
      for (int mt=0;mt<8;mt++){
        int p0 = mt*16 + quad*4;
        f32x4 v = acc[nt][mt];
        u32 lo = ((u32)f2bf(v.y)<<16) | (u32)f2bf(v.x);
        u32 hi = ((u32)f2bf(v.w)<<16) | (u32)f2bf(v.z);
        int d = (p0>>3) ^ (och&7);
        u32* dst = (u32*)&s_spec[och*128 + d*8 + (p0&7)];
        dst[0] = lo; dst[1] = hi;
      }
    }
  };

  // read 64 pixels of (pc, c) from swizzled s_spec into p[64] ([row][col] packed)
  auto read_spec = [&](float* p){
    #pragma unroll
    for (int d=0; d<8; d++){
      int cz = (pc*8+d) ^ (c&7);
      const uint4 q4 = *(const uint4*)&s_spec[c*128 + cz*8];
      u32 ws4[4] = {q4.x, q4.y, q4.z, q4.w};
      #pragma unroll
      for (int e=0;e<4;e++){
        p[d*8+2*e]   = bf2f((u16)(ws4[e] & 0xFFFFu));
        p[d*8+2*e+1] = bf2f((u16)(ws4[e] >> 16));
      }
    }
  };

  // ---- phase A: event ----
  do_stage(evt);
  __syncthreads();
  do_gemm(wbe);
  __syncthreads();

  // ---- FFT1: Fe = rfft2(evt_), fef = Fe * filter ----
  C2 fef[8][5];
  {
    float p[64];
    read_spec(p);
    #pragma unroll
    for (int r=0;r<8;r++) rfft8_row(&p[r*8]);
    const float* fl = filt + c*40;
    #pragma unroll
    for (int j=0;j<5;j++){
      C2 yv[8];
      #pragma unroll
      for (int r=0;r<8;r++){
        float re = (j==0) ? p[r*8] : (j==4) ? p[r*8+1] : p[r*8+2*j];
        float im = (j==0 || j==4) ? 0.f : p[r*8+2*j+1];
        yv[r].r = re; yv[r].i = im;
      }
      fft8_fwd(yv);
      #pragma unroll
      for (int ky=0;ky<8;ky++){
        float f = fl[ky*5+j];
        fef[ky][j].r = yv[ky].r * f;
        fef[ky][j].i = yv[ky].i * f;
      }
    }
  }

  // ---- stage img (s_a free since GEMM-evt done) ----
  do_stage(img);
  __syncthreads();
  do_gemm(wbi);
  __syncthreads();

  // ---- FFT2: X = (Fi+1)*fef ; x = irfft2(X) ----
  {
    float p[64];
    read_spec(p);
    #pragma unroll
    for (int r=0;r<8;r++) rfft8_row(&p[r*8]);
    #pragma unroll
    for (int j=0;j<5;j++){
      C2 yv[8];
      #pragma unroll
      for (int r=0;r<8;r++){
        float re = (j==0) ? p[r*8] : (j==4) ? p[r*8+1] : p[r*8+2*j];
        float im = (j==0 || j==4) ? 0.f : p[r*8+2*j+1];
        yv[r].r = re; yv[r].i = im;
      }
      fft8_fwd(yv);
      #pragma unroll
      for (int ky=0;ky<8;ky++){
        C2 e = fef[ky][j];
        C2 a = yv[ky];
        fef[ky][j].r = a.r*e.r - a.i*e.i + e.r;
        fef[ky][j].i = a.r*e.i + a.i*e.r + e.i;
      }
    }
    #pragma unroll
    for (int j=0;j<5;j++){
      C2 z[8];
      #pragma unroll
      for (int ky=0;ky<8;ky++) z[ky] = fef[ky][j];
      fft8_inv(z);
      #pragma unroll
      for (int ky=0;ky<8;ky++) fef[ky][j] = z[ky];
    }
    #pragma unroll
    for (int r=0;r<8;r++)
      irfft8_row(fef[r][0].r, fef[r][1], fef[r][2], fef[r][3], fef[r][4].r, &p[r*8]);

    __syncthreads();   // all reads of s_spec done; reuse as stage
    #pragma unroll
    for (int k=0;k<64;k++)
      s_spec[(pc*64 + k)*128 + c] = f2bf(p[k]);
  }
  __syncthreads();

  // ---- coalesced store (32 KB) ----
  {
    const uint4* sg = (const uint4*)s_spec;
    uint4* dst = (uint4*)(yout + (size_t)(b*1024 + ph*32 + bx*2)*8192);
    #pragma unroll
    for (int i=0;i<8;i++){
      int q2 = t + 256*i;
      dst[q2] = sg[q2];
    }
  }
}

// ---------------- K_back: dw3x3 + gelu-gate + 1x1 out (MFMA) ----------------
// block = 16x16 pixel tile, 256 threads
__global__ __launch_bounds__(256, 3)
void k_back(const u16* __restrict__ y, const float* __restrict__ wdw,
            const u16* __restrict__ wbo, float* __restrict__ out){
  __shared__ __align__(16) u16 L[18*20*36];   // 25920 B halo tile: [py 18][px 20][c 32 +4 pad]
  __shared__ __align__(16) u16 A[256*48];     // 24576 B act: [pix 256][c 32 +16 pad]

  const int t   = threadIdx.x;
  const int bid = blockIdx.x;     // 1024 = b(4) * ty(16) * tx(16)
  const int b   = bid >> 8;
  const int ty  = (bid >> 4) & 15;
  const int tx  = bid & 15;
  const int wv   = t >> 6;
  const int quad = (t >> 4) & 3;
  const int ln15 = t & 15;
  const int y_  = t >> 4, x_ = t & 15;

  f32x4 acc[4][4];
  #pragma unroll
  for (int mt=0;mt<4;mt++)
    #pragma unroll
    for (int nt=0;nt<4;nt++)
      acc[mt][nt] = (f32x4){0.f,0.f,0.f,0.f};

  // load 18x18 halo x 32 channels (cbase..cbase+31) into L
  auto load32 = [&](int cbase){
    #pragma unroll
    for (int i=0;i<6;i++){
      int task = t + 256*i;
      if (task < 1296){
        int q = task & 3, pix = task >> 2;
        int py = pix / 18, px = pix - py*18;
        int gy = ty*16 - 1 + py, gx = tx*16 - 1 + px;
        uint4 v = make_uint4(0u,0u,0u,0u);
        if ((unsigned)gy < 256u && (unsigned)gx < 256u){
          int phh = gy>>3, pww = gx>>3, k = (gy&7)*8 + (gx&7);
          v = *(const uint4*)&y[(((size_t)(b*1024 + phh*32 + pww))*64 + k)*128 + cbase + q*8];
        }
        int addr = (py*20+px)*36 + q*8;
        *(uint2*)&L[addr]     = make_uint2(v.x, v.y);
        *(uint2*)&L[addr + 4] = make_uint2(v.z, v.w);
      }
    }
  };

  float d1v[32];

  for (int chunk=0; chunk<2; chunk++){
    // ---- d1 half: channels chunk*32.. ----
    load32(chunk*32);
    __syncthreads();
    #pragma unroll
    for (int cg=0; cg<8; cg++){
      float d[4] = {0.f,0.f,0.f,0.f};
      const float* wp0 = wdw + (chunk*32 + cg*4)*9;
      #pragma unroll
      for (int dy=0; dy<3; dy++)
        #pragma unroll
        for (int dx=0; dx<3; dx++){
          const uint2 a = *(const uint2*)&L[((y_+dy)*20 + (x_+dx))*36 + cg*4];
          const float* wp = wp0 + dy*3 + dx;
          d[0] = fmaf(wp[0],  bf2f((u16)(a.x & 0xFFFFu)), d[0]);
          d[1] = fmaf(wp[9],  bf2f((u16)(a.x >> 16)),     d[1]);
          d[2] = fmaf(wp[18], bf2f((u16)(a.y & 0xFFFFu)), d[2]);
          d[3] = fmaf(wp[27], bf2f((u16)(a.y >> 16)),     d[3]);
        }
      #pragma unroll
      for (int l=0;l<4;l++) d1v[cg*4+l] = d[l];
    }
    __syncthreads();

    // ---- d2 half: channels 64+chunk*32.. ; act -> A ----
    load32(64 + chunk*32);
    __syncthreads();
    #pragma unroll
    for (int cg=0; cg<8; cg++){
      float d[4] = {0.f,0.f,0.f,0.f};
      const float* wp0 = wdw + (64 + chunk*32 + cg*4)*9;
      #pragma unroll
      for (int dy=0; dy<3; dy++)
        #pragma unroll
        for (int dx=0; dx<3; dx++){
          const uint2 a = *(const uint2*)&L[((y_+dy)*20 + (x_+dx))*36 + cg*4];
          const float* wp = wp0 + dy*3 + dx;
          d[0] = fmaf(wp[0],  bf2f((u16)(a.x & 0xFFFFu)), d[0]);
          d[1] = fmaf(wp[9],  bf2f((u16)(a.x >> 16)),     d[1]);
          d[2] = fmaf(wp[18], bf2f((u16)(a.y & 0xFFFFu)), d[2]);
          d[3] = fmaf(wp[27], bf2f((u16)(a.y >> 16)),     d[3]);
        }
      u16 h[4];
      #pragma unroll
      for (int l=0;l<4;l++){
        float g1 = d1v[cg*4+l];
        float g = 0.5f * g1 * (1.f + erff(g1 * 0.70710678118654752f));
        h[l] = f2bf(g * d[l]);
      }
      *(uint2*)&A[t*48 + cg*4] =
          make_uint2(((u32)h[1]<<16) | h[0], ((u32)h[3]<<16) | h[2]);
    }
    __syncthreads();

    // ---- GEMM: acc += act[pix][k32] * w_out[och][k32] ----
    bf16x8 bfr[4];
    #pragma unroll
    for (int nt=0;nt<4;nt++)
      bfr[nt] = *(const bf16x8*)&wbo[(nt*16 + ln15)*64 + chunk*32 + quad*8];
    #pragma unroll
    for (int mt=0;mt<4;mt++){
      bf16x8 af = *(const bf16x8*)&A[(wv*64 + mt*16 + ln15)*48 + quad*8];
      #pragma unroll
      for (int nt=0;nt<4;nt++)
        acc[mt][nt] = MFMA(af, bfr[nt], acc[mt][nt]);
    }
    // next chunk's load32 only touches L; act-read hazard covered by the
    // two barriers before the next A-write.
  }

  // ---- epilogue: coalesced float4 stores ----
  #pragma unroll
  for (int mt=0;mt<4;mt++){
    int row = ty*16 + wv*4 + mt;
    #pragma unroll
    for (int nt=0;nt<4;nt++){
      int och = nt*16 + ln15;
      f32x4 v = acc[mt][nt];
      float4 o4 = make_float4(v.x, v.y, v.z, v.w);
      *(float4*)(out + (((size_t)(b*64 + och))*256 + row)*256 + tx*16 + quad*4) = o4;
    }
  }
}

extern "C" void kernel_launch(void* const* d_in, const int* in_sizes, int n_in,
                              void* d_out, int out_size, void* d_ws, size_t ws_size,
                              hipStream_t stream){
  const float* img   = (const float*)d_in[0];
  const float* evt   = (const float*)d_in[1];
  const float* w_img = (const float*)d_in[2];
  const float* w_evt = (const float*)d_in[3];
  const float* w_dw  = (const float*)d_in[4];
  const float* filt  = (const float*)d_in[5];
  const float* w_out = (const float*)d_in[6];
  float* out = (float*)d_out;

  u16* wbi = (u16*)d_ws;                          // 16 KB
  u16* wbe = (u16*)((char*)d_ws + 16384);         // 16 KB
  u16* wbo = (u16*)((char*)d_ws + 32768);         //  8 KB
  u16* y   = (u16*)((char*)d_ws + 65536);         // 67.1 MB bf16 intermediate

  k_prep<<<80, 256, 0, stream>>>(w_img, w_evt, w_out, wbi, wbe, wbo);
  k_front<<<2048, 256, 0, stream>>>(img, evt, wbi, wbe, filt, y);
  k_back<<<1024, 256, 0, stream>>>(y, w_dw, wbo, out);
}

// Round 3
// 304.823 us; speedup vs baseline: 1.9666x; 1.6060x over previous
//
#include <hip/hip_runtime.h>
#include <math.h>

typedef unsigned short u16;
typedef unsigned int   u32;

#define S2 0.70710678118654752440f

typedef float f32x4 __attribute__((ext_vector_type(4)));
typedef short bf16x8 __attribute__((ext_vector_type(8)));
#define MFMA(a,b,c) __builtin_amdgcn_mfma_f32_16x16x32_bf16(a,b,c,0,0,0)

__device__ __forceinline__ float bf2f(u16 u){
  union { u32 i; float f; } v; v.i = ((u32)u) << 16; return v.f;
}
__device__ __forceinline__ u16 f2bf(float f){
  union { float f; u32 i; } v; v.f = f;
  u32 r = v.i + 0x7FFFu + ((v.i >> 16) & 1u);
  return (u16)(r >> 16);
}

struct C2 { float r, i; };

__device__ __forceinline__ void fft8_fwd(C2* y){
  C2 a0 = {y[0].r+y[4].r, y[0].i+y[4].i};
  C2 a1 = {y[0].r-y[4].r, y[0].i-y[4].i};
  C2 a2 = {y[2].r+y[6].r, y[2].i+y[6].i};
  C2 a3 = {y[2].r-y[6].r, y[2].i-y[6].i};
  C2 b0 = {y[1].r+y[5].r, y[1].i+y[5].i};
  C2 b1 = {y[1].r-y[5].r, y[1].i-y[5].i};
  C2 b2 = {y[3].r+y[7].r, y[3].i+y[7].i};
  C2 b3 = {y[3].r-y[7].r, y[3].i-y[7].i};
  C2 E0 = {a0.r+a2.r, a0.i+a2.i};
  C2 E2 = {a0.r-a2.r, a0.i-a2.i};
  C2 E1 = {a1.r+a3.i, a1.i-a3.r};
  C2 E3 = {a1.r-a3.i, a1.i+a3.r};
  C2 O0 = {b0.r+b2.r, b0.i+b2.i};
  C2 O2 = {b0.r-b2.r, b0.i-b2.i};
  C2 O1 = {b1.r+b3.i, b1.i-b3.r};
  C2 O3 = {b1.r-b3.i, b1.i+b3.r};
  C2 t1 = {S2*(O1.r+O1.i), S2*(O1.i-O1.r)};
  C2 t2 = {O2.i, -O2.r};
  C2 t3 = {S2*(O3.i-O3.r), -S2*(O3.r+O3.i)};
  y[0].r=E0.r+O0.r; y[0].i=E0.i+O0.i;
  y[4].r=E0.r-O0.r; y[4].i=E0.i-O0.i;
  y[1].r=E1.r+t1.r; y[1].i=E1.i+t1.i;
  y[5].r=E1.r-t1.r; y[5].i=E1.i-t1.i;
  y[2].r=E2.r+t2.r; y[2].i=E2.i+t2.i;
  y[6].r=E2.r-t2.r; y[6].i=E2.i-t2.i;
  y[3].r=E3.r+t3.r; y[3].i=E3.i+t3.i;
  y[7].r=E3.r-t3.r; y[7].i=E3.i-t3.i;
}

__device__ __forceinline__ void fft8_inv(C2* z){
  C2 A0 = {z[0].r+z[4].r, z[0].i+z[4].i};
  C2 A1 = {z[1].r+z[5].r, z[1].i+z[5].i};
  C2 A2 = {z[2].r+z[6].r, z[2].i+z[6].i};
  C2 A3 = {z[3].r+z[7].r, z[3].i+z[7].i};
  C2 D0 = {z[0].r-z[4].r, z[0].i-z[4].i};
  C2 D1 = {z[1].r-z[5].r, z[1].i-z[5].i};
  C2 D2 = {z[2].r-z[6].r, z[2].i-z[6].i};
  C2 D3 = {z[3].r-z[7].r, z[3].i-z[7].i};
  C2 B0 = D0;
  C2 B1 = {S2*(D1.r-D1.i), S2*(D1.i+D1.r)};
  C2 B2 = {-D2.i, D2.r};
  C2 B3 = {-S2*(D3.r+D3.i), S2*(D3.r-D3.i)};
  z[0].r = A0.r+A1.r+A2.r+A3.r;           z[0].i = A0.i+A1.i+A2.i+A3.i;
  z[2].r = A0.r-A2.r-(A1.i-A3.i);         z[2].i = A0.i-A2.i+(A1.r-A3.r);
  z[4].r = A0.r-A1.r+A2.r-A3.r;           z[4].i = A0.i-A1.i+A2.i-A3.i;
  z[6].r = A0.r-A2.r+(A1.i-A3.i);         z[6].i = A0.i-A2.i-(A1.r-A3.r);
  z[1].r = B0.r+B1.r+B2.r+B3.r;           z[1].i = B0.i+B1.i+B2.i+B3.i;
  z[3].r = B0.r-B2.r-(B1.i-B3.i);         z[3].i = B0.i-B2.i+(B1.r-B3.r);
  z[5].r = B0.r-B1.r+B2.r-B3.r;           z[5].i = B0.i-B1.i+B2.i-B3.i;
  z[7].r = B0.r-B2.r+(B1.i-B3.i);         z[7].i = B0.i-B2.i-(B1.r-B3.r);
}

__device__ __forceinline__ void rfft8_row(float* x){
  float et0=x[0]+x[4], et1=x[0]-x[4], et2=x[2]+x[6], et3=x[2]-x[6];
  float ot0=x[1]+x[5], ot1=x[1]-x[5], ot2=x[3]+x[7], ot3=x[3]-x[7];
  float E0=et0+et2, E2=et0-et2;
  float O0=ot0+ot2, O2=ot0-ot2;
  float om=S2*(ot1-ot3), op=S2*(ot1+ot3);
  x[0]=E0+O0;  x[1]=E0-O0;
  x[2]=et1+om; x[3]=-et3-op;
  x[4]=E2;     x[5]=-O2;
  x[6]=et1-om; x[7]=et3-op;
}

__device__ __forceinline__ void irfft8_row(float f0, C2 R1, C2 R2, C2 R3, float f4, float* x){
  float A0  = f0+f4, B0v = f0-f4;
  float A1r = R1.r+R3.r, A1i = R1.i-R3.i;
  float A2  = 2.f*R2.r;
  float D1r = R1.r-R3.r, D1i = R1.i+R3.i;
  float B1r = S2*(D1r-D1i), B1i = S2*(D1i+D1r);
  float B2  = -2.f*R2.i;
  const float k = 1.f/64.f;
  x[0]=k*(A0 +A2+2.f*A1r); x[2]=k*(A0 -A2-2.f*A1i);
  x[4]=k*(A0 +A2-2.f*A1r); x[6]=k*(A0 -A2+2.f*A1i);
  x[1]=k*(B0v+B2+2.f*B1r); x[3]=k*(B0v-B2-2.f*B1i);
  x[5]=k*(B0v+B2-2.f*B1r); x[7]=k*(B0v-B2+2.f*B1i);
}

// ---------------- K_prep: fp32 weights -> bf16 ----------------
__global__ void k_prep(const float* __restrict__ wi, const float* __restrict__ we,
                       const float* __restrict__ wo,
                       u16* __restrict__ wbi, u16* __restrict__ wbe, u16* __restrict__ wbo){
  int i = blockIdx.x*256 + threadIdx.x;   // 20480
  if (i < 8192)        wbi[i]        = f2bf(wi[i]);
  else if (i < 16384)  wbe[i-8192]   = f2bf(we[i-8192]);
  else if (i < 20480)  wbo[i-16384]  = f2bf(wo[i-16384]);
}

// ---------------- K_front: 1x1 convs (MFMA) + patch FFT ----------------
// block = 2 horizontal patches (128 pixels), 256 threads
// y layout (bf16): [b][ph(32)][pw(32)][k=r*8+col (64)][c' (128)] where
// c' = (c&31)|((c&32)<<1)|((c&64)>>1)  (chunk-contiguous permutation for k_back)
__global__ __launch_bounds__(256, 2)
void k_front(const float* __restrict__ img, const float* __restrict__ evt,
             const u16* __restrict__ wbi, const u16* __restrict__ wbe,
             const float* __restrict__ filt, u16* __restrict__ yout){
  __shared__ __align__(16) u16 s_a[8192];      // 16 KB  [pix(128)][c(64)] xor-swizzled
  __shared__ __align__(16) u16 s_spec[16384];  // 32 KB  [och(128)][pix(128)] swizzled / stage

  const int t   = threadIdx.x;
  const int bid = blockIdx.x;          // 2048 = b(4) * ph(32) * bx(16)
  const int b   = bid >> 9;
  const int ph  = (bid >> 4) & 31;
  const int bx  = bid & 15;
  const int wv   = t >> 6;
  const int quad = (t >> 4) & 3;
  const int ln15 = t & 15;
  const int pc   = t >> 7;             // fft patch (0/1)
  const int c    = t & 127;            // fft channel (original index)

  auto do_stage = [&](const float* src){
    #pragma unroll
    for (int i=0;i<8;i++){
      int task = t + 256*i;
      int ci = task>>5, q = task&31;
      int r = q>>2, j = q&3;
      const float4 v = *(const float4*)(src +
          (((size_t)(b*64+ci)*256 + ph*8 + r)*256 + bx*16 + j*4));
      int p0 = (j>>1)*64 + r*8 + (j&1)*4;
      int gbase = ci>>3, cl = ci&7;
      float vv[4] = {v.x, v.y, v.z, v.w};
      #pragma unroll
      for (int w=0;w<4;w++){
        int p = p0+w;
        int g = gbase ^ (p&7) ^ r;
        s_a[p*64 + g*8 + cl] = f2bf(vv[w]);
      }
    }
  };

  auto do_gemm = [&](const u16* __restrict__ wb){
    f32x4 acc[2][8];
    #pragma unroll
    for (int nt=0;nt<2;nt++)
      #pragma unroll
      for (int mt=0;mt<8;mt++)
        acc[nt][mt] = (f32x4){0.f,0.f,0.f,0.f};
    const int nb = wv*32;
    #pragma unroll
    for (int kk=0;kk<2;kk++){
      bf16x8 bf0 = *(const bf16x8*)&wb[(nb      + ln15)*64 + kk*32 + quad*8];
      bf16x8 bf1 = *(const bf16x8*)&wb[(nb + 16 + ln15)*64 + kk*32 + quad*8];
      #pragma unroll
      for (int mt=0;mt<8;mt++){
        int pix = mt*16 + ln15;
        int g = (kk*4+quad) ^ (pix&7) ^ ((pix>>3)&7);
        bf16x8 af = *(const bf16x8*)&s_a[pix*64 + g*8];
        acc[0][mt] = MFMA(af, bf0, acc[0][mt]);
        acc[1][mt] = MFMA(af, bf1, acc[1][mt]);
      }
    }
    #pragma unroll
    for (int nt=0;nt<2;nt++){
      int och = nb + nt*16 + ln15;
      #pragma unroll
      for (int mt=0;mt<8;mt++){
        int p0 = mt*16 + quad*4;
        f32x4 v = acc[nt][mt];
        u32 lo = ((u32)f2bf(v.y)<<16) | (u32)f2bf(v.x);
        u32 hi = ((u32)f2bf(v.w)<<16) | (u32)f2bf(v.z);
        int d = (p0>>3) ^ (och&7);
        u32* dst = (u32*)&s_spec[och*128 + d*8 + (p0&7)];
        dst[0] = lo; dst[1] = hi;
      }
    }
  };

  auto read_spec = [&](float* p){
    #pragma unroll
    for (int d=0; d<8; d++){
      int cz = (pc*8+d) ^ (c&7);
      const uint4 q4 = *(const uint4*)&s_spec[c*128 + cz*8];
      u32 ws4[4] = {q4.x, q4.y, q4.z, q4.w};
      #pragma unroll
      for (int e=0;e<4;e++){
        p[d*8+2*e]   = bf2f((u16)(ws4[e] & 0xFFFFu));
        p[d*8+2*e+1] = bf2f((u16)(ws4[e] >> 16));
      }
    }
  };

  // ---- event: stage -> GEMM -> row spectra ----
  do_stage(evt);
  __syncthreads();
  do_gemm(wbe);
  __syncthreads();

  float pe[64];
  read_spec(pe);
  #pragma unroll
  for (int r=0;r<8;r++) rfft8_row(&pe[r*8]);

  // ---- img: stage (overlaps pe FFT) -> GEMM ----
  do_stage(img);
  __syncthreads();          // covers: pe reads done + s_a img visible
  do_gemm(wbi);
  __syncthreads();

  // ---- FFT2: merged columns, X = (Fi+1)*(Fe*f) ----
  float pi[64];
  read_spec(pi);
  __syncthreads();          // all s_spec reads done; safe to overwrite below
  #pragma unroll
  for (int r=0;r<8;r++) rfft8_row(&pi[r*8]);

  C2 X[8][5];
  {
    const float* fl = filt + c*40;
    #pragma unroll
    for (int j=0;j<5;j++){
      C2 e8[8], i8[8];
      #pragma unroll
      for (int r=0;r<8;r++){
        float re_e, im_e, re_i, im_i;
        if (j==0){ re_e=pe[r*8];   im_e=0.f; re_i=pi[r*8];   im_i=0.f; }
        else if (j==4){ re_e=pe[r*8+1]; im_e=0.f; re_i=pi[r*8+1]; im_i=0.f; }
        else { re_e=pe[r*8+2*j]; im_e=pe[r*8+2*j+1];
               re_i=pi[r*8+2*j]; im_i=pi[r*8+2*j+1]; }
        e8[r].r=re_e; e8[r].i=im_e; i8[r].r=re_i; i8[r].i=im_i;
      }
      fft8_fwd(e8);
      fft8_fwd(i8);
      #pragma unroll
      for (int ky=0;ky<8;ky++){
        float f  = fl[ky*5+j];
        float fr = e8[ky].r*f, fi2 = e8[ky].i*f;
        X[ky][j].r = i8[ky].r*fr - i8[ky].i*fi2 + fr;
        X[ky][j].i = i8[ky].r*fi2 + i8[ky].i*fr + fi2;
      }
    }
    #pragma unroll
    for (int j=0;j<5;j++){
      C2 z[8];
      #pragma unroll
      for (int ky=0;ky<8;ky++) z[ky] = X[ky][j];
      fft8_inv(z);
      #pragma unroll
      for (int ky=0;ky<8;ky++) X[ky][j] = z[ky];
    }
  }

  // row irffts -> stage writes (channel-permuted)
  {
    const int cp = (c&31) | ((c&32)<<1) | ((c&64)>>1);
    #pragma unroll
    for (int r=0;r<8;r++){
      float xr[8];
      irfft8_row(X[r][0].r, X[r][1], X[r][2], X[r][3], X[r][4].r, xr);
      #pragma unroll
      for (int n2=0;n2<8;n2++)
        s_spec[(pc*64 + r*8 + n2)*128 + cp] = f2bf(xr[n2]);
    }
  }
  __syncthreads();

  // ---- coalesced store (32 KB) ----
  {
    const uint4* sg = (const uint4*)s_spec;
    uint4* dst = (uint4*)(yout + (size_t)(b*1024 + ph*32 + bx*2)*8192);
    #pragma unroll
    for (int i=0;i<8;i++){
      int q2 = t + 256*i;
      dst[q2] = sg[q2];
    }
  }
}

// ---------------- K_back: dw3x3 + gelu-gate + 1x1 out (MFMA) ----------------
// block = 16x16 pixel tile, 256 threads. Reads permuted y: chunk ch = 128 B contiguous.
__global__ __launch_bounds__(256, 2)
void k_back(const u16* __restrict__ y, const float* __restrict__ wdw,
            const u16* __restrict__ wbo, float* __restrict__ out){
  __shared__ __align__(16) u16 L[18*19*68];   // 46512 B: [py 18][px 19][ch 64 +4 pad]
  __shared__ __align__(16) u16 A[256*32];     // 16384 B: [pix 256][ch 32] xor-swizzled

  const int t   = threadIdx.x;
  const int bid = blockIdx.x;     // 1024 = b(4) * ty(16) * tx(16)
  const int b   = bid >> 8;
  const int ty  = (bid >> 4) & 15;
  const int tx  = bid & 15;
  const int wv   = t >> 6;
  const int quad = (t >> 4) & 3;
  const int ln15 = t & 15;
  const int y_  = t >> 4, x_ = t & 15;
  const int sw  = (t&3) ^ ((t>>2)&3);

  f32x4 acc[4][4];
  #pragma unroll
  for (int mt=0;mt<4;mt++)
    #pragma unroll
    for (int nt=0;nt<4;nt++)
      acc[mt][nt] = (f32x4){0.f,0.f,0.f,0.f};

  for (int chunk=0; chunk<2; chunk++){
    // ---- halo load: 324 pixels x 128 B contiguous each ----
    for (int i=0;i<11;i++){
      int task = t + 256*i;
      if (task < 2592){
        int q = task & 7, pix = task >> 3;
        int py = pix/18, px = pix - py*18;
        int gy = ty*16 - 1 + py, gx = tx*16 - 1 + px;
        uint4 v = make_uint4(0u,0u,0u,0u);
        if ((unsigned)gy < 256u && (unsigned)gx < 256u){
          int phh = gy>>3, pww = gx>>3, k = (gy&7)*8 + (gx&7);
          v = *(const uint4*)&y[(((size_t)(b*1024 + phh*32 + pww))*64 + k)*128
                                + chunk*64 + q*8];
        }
        int ad = (py*19+px)*68 + q*8;
        *(uint2*)&L[ad]     = make_uint2(v.x, v.y);
        *(uint2*)&L[ad + 4] = make_uint2(v.z, v.w);
      }
    }
    __syncthreads();

    // ---- dwconv pair + gelu gate -> A ----
    #pragma unroll
    for (int cg=0; cg<8; cg++){
      float d1[4] = {0.f,0.f,0.f,0.f};
      float d2[4] = {0.f,0.f,0.f,0.f};
      const float* w1p = wdw + (chunk*32 + cg*4)*9;
      const float* w2p = wdw + (64 + chunk*32 + cg*4)*9;
      #pragma unroll
      for (int dy=0; dy<3; dy++)
        #pragma unroll
        for (int dx=0; dx<3; dx++){
          int base = ((y_+dy)*19 + (x_+dx))*68;
          const uint2 a1 = *(const uint2*)&L[base + cg*4];
          const uint2 a2 = *(const uint2*)&L[base + 32 + cg*4];
          const float* wp1 = w1p + dy*3 + dx;
          const float* wp2 = w2p + dy*3 + dx;
          d1[0] = fmaf(wp1[0],  bf2f((u16)(a1.x & 0xFFFFu)), d1[0]);
          d1[1] = fmaf(wp1[9],  bf2f((u16)(a1.x >> 16)),     d1[1]);
          d1[2] = fmaf(wp1[18], bf2f((u16)(a1.y & 0xFFFFu)), d1[2]);
          d1[3] = fmaf(wp1[27], bf2f((u16)(a1.y >> 16)),     d1[3]);
          d2[0] = fmaf(wp2[0],  bf2f((u16)(a2.x & 0xFFFFu)), d2[0]);
          d2[1] = fmaf(wp2[9],  bf2f((u16)(a2.x >> 16)),     d2[1]);
          d2[2] = fmaf(wp2[18], bf2f((u16)(a2.y & 0xFFFFu)), d2[2]);
          d2[3] = fmaf(wp2[27], bf2f((u16)(a2.y >> 16)),     d2[3]);
        }
      u16 h[4];
      #pragma unroll
      for (int l=0;l<4;l++){
        float g1 = d1[l];
        float g = 0.5f * g1 * (1.f + erff(g1 * 0.70710678118654752f));
        h[l] = f2bf(g * d2[l]);
      }
      int pos = ((cg>>1) ^ sw)*8 + (cg&1)*4;
      *(uint2*)&A[t*32 + pos] =
          make_uint2(((u32)h[1]<<16) | h[0], ((u32)h[3]<<16) | h[2]);
    }
    __syncthreads();

    // ---- GEMM: acc += act[pix][k32] * w_out[och][k32] ----
    bf16x8 bfr[4];
    #pragma unroll
    for (int nt=0;nt<4;nt++)
      bfr[nt] = *(const bf16x8*)&wbo[(nt*16 + ln15)*64 + chunk*32 + quad*8];
    #pragma unroll
    for (int mt=0;mt<4;mt++){
      int px8 = wv*64 + mt*16 + ln15;
      int q2 = quad ^ ((px8&3) ^ ((px8>>2)&3));
      bf16x8 af = *(const bf16x8*)&A[px8*32 + q2*8];
      #pragma unroll
      for (int nt=0;nt<4;nt++)
        acc[mt][nt] = MFMA(af, bfr[nt], acc[mt][nt]);
    }
    __syncthreads();   // A reads done before next chunk overwrites L/A
  }

  // ---- epilogue: coalesced float4 stores ----
  #pragma unroll
  for (int mt=0;mt<4;mt++){
    int row = ty*16 + wv*4 + mt;
    #pragma unroll
    for (int nt=0;nt<4;nt++){
      int och = nt*16 + ln15;
      f32x4 v = acc[mt][nt];
      float4 o4 = make_float4(v.x, v.y, v.z, v.w);
      *(float4*)(out + (((size_t)(b*64 + och))*256 + row)*256 + tx*16 + quad*4) = o4;
    }
  }
}

extern "C" void kernel_launch(void* const* d_in, const int* in_sizes, int n_in,
                              void* d_out, int out_size, void* d_ws, size_t ws_size,
                              hipStream_t stream){
  const float* img   = (const float*)d_in[0];
  const float* evt   = (const float*)d_in[1];
  const float* w_img = (const float*)d_in[2];
  const float* w_evt = (const float*)d_in[3];
  const float* w_dw  = (const float*)d_in[4];
  const float* filt  = (const float*)d_in[5];
  const float* w_out = (const float*)d_in[6];
  float* out = (float*)d_out;

  u16* wbi = (u16*)d_ws;                          // 16 KB
  u16* wbe = (u16*)((char*)d_ws + 16384);         // 16 KB
  u16* wbo = (u16*)((char*)d_ws + 32768);         //  8 KB
  u16* y   = (u16*)((char*)d_ws + 65536);         // 67.1 MB bf16 intermediate

  k_prep<<<80, 256, 0, stream>>>(w_img, w_evt, w_out, wbi, wbe, wbo);
  k_front<<<2048, 256, 0, stream>>>(img, evt, wbi, wbe, filt, y);
  k_back<<<1024, 256, 0, stream>>>(y, w_dw, wbo, out);
}